// Round 5
// baseline (79.880 us; speedup 1.0000x reference)
//
#include <hip/hip_runtime.h>

// DiversityLoss: pose (K=32, B=32, T=64, E=63) fp32.
// feat[bt,k,e] = pose[k, b, t, e], bt = b*64+t.
// loss = sum_{bt} sum_{i<j} exp(-L1(feat[bt,i], feat[bt,j])) / (BT*K*(K-1)/2)
// Off-diagonal sum computed directly (both triangles, then halve) — diagonal
// exp(0)=1 terms would absorb the ~1e-18 off-diagonal terms in fp32.
//
// Structure: 1 block (128 thr, 2 waves) per bt slice; waves split the e-dim
// (32 elems each) keeping the 4x4 register tile (minimal LDS reads/pair).
// 2048 blocks x 2 waves = 16 waves/CU (4/SIMD), 8.9 KB LDS -> ALL blocks
// resident in a single dispatch round (no straggler tail; round-3's 256-thr
// version needed 8 blocks/CU but VGPR capped residency at 7).
// Per-wave partials exchanged as float4 (conflict-free b128), buffer aliases
// the feat tile. NO global atomics (round-4 fusion via agent-scope atomics
// cost 3x — cache-invalidate serialization).

#define KDIM 32
#define EDIM 63
#define STRIDE 68      // feat row stride (dwords): 16B-aligned; 68%32=4 spreads rows over banks
#define BT_TOTAL 2048
#define CNT 1015808.0f // 2048 * 32*31/2

__global__ __launch_bounds__(128, 4) void divloss_pairs(const float* __restrict__ pose,
                                                        float* __restrict__ ws) {
    // feat tile: 32*68 = 2176 dw (8704 B). part4 (8*64 float4 = 8192 B) aliases it.
    __shared__ float smem[2176];
    __shared__ float wsum[2];
    float* feat = smem;
    float4* part4 = reinterpret_cast<float4*>(smem);

    const int bt = blockIdx.x;
    const int wv = threadIdx.x >> 6;    // 0..1
    const int lane = threadIdx.x & 63;  // 0..63

    // Stage feat[bt]: wave wv loads rows 16*wv .. 16*wv+15 (63 floats, pad e=63 with 0).
    #pragma unroll
    for (int r = 0; r < 16; ++r) {
        const int k = 16 * wv + r;
        float v = 0.0f;
        if (lane < EDIM) v = pose[(k * BT_TOTAL + bt) * EDIM + lane];
        feat[k * STRIDE + lane] = v;
    }
    __syncthreads();

    const int ti = lane >> 3;   // rows {ti, ti+8, ti+16, ti+24}
    const int tj = lane & 7;    // cols {tj, tj+8, tj+16, tj+24}

    float acc[4][4] = {};

    // Wave wv covers e-chunks 8*wv .. 8*wv+7 (32 e-elems; wave 1 includes the pad).
    #pragma unroll
    for (int i = 0; i < 8; ++i) {
        const int ec = 8 * wv + i;
        float4 a[4], b[4];
        #pragma unroll
        for (int r = 0; r < 4; ++r)
            a[r] = *reinterpret_cast<const float4*>(&feat[(ti + 8 * r) * STRIDE + 4 * ec]);
        #pragma unroll
        for (int c = 0; c < 4; ++c)
            b[c] = *reinterpret_cast<const float4*>(&feat[(tj + 8 * c) * STRIDE + 4 * ec]);
        #pragma unroll
        for (int r = 0; r < 4; ++r)
            #pragma unroll
            for (int c = 0; c < 4; ++c) {
                acc[r][c] += fabsf(a[r].x - b[c].x) + fabsf(a[r].y - b[c].y)
                           + fabsf(a[r].z - b[c].z) + fabsf(a[r].w - b[c].w);
            }
    }

    __syncthreads();   // all feat reads done; safe to overwrite with partials

    // Exchange: wave wv writes acc[r][0..3] as one float4 at entry (wv*4+r).
    // Lane stride 16B -> conflict-free ds_write_b128.
    #pragma unroll
    for (int r = 0; r < 4; ++r)
        part4[(wv * 4 + r) * 64 + lane] = make_float4(acc[r][0], acc[r][1], acc[r][2], acc[r][3]);
    __syncthreads();

    // Wave wv finalizes r in {2wv, 2wv+1}: d = partial(wave0) + partial(wave1),
    // exp, mask diagonal pairs (ti==tj && c==r), accumulate both triangles.
    float s = 0.0f;
    #pragma unroll
    for (int rr = 0; rr < 2; ++rr) {
        const int r = 2 * wv + rr;
        float4 p0 = part4[(0 * 4 + r) * 64 + lane];
        float4 p1 = part4[(1 * 4 + r) * 64 + lane];
        float e0 = __expf(-(p0.x + p1.x));
        float e1 = __expf(-(p0.y + p1.y));
        float e2 = __expf(-(p0.z + p1.z));
        float e3 = __expf(-(p0.w + p1.w));
        s += ((ti == tj) && (r == 0)) ? 0.0f : e0;
        s += ((ti == tj) && (r == 1)) ? 0.0f : e1;
        s += ((ti == tj) && (r == 2)) ? 0.0f : e2;
        s += ((ti == tj) && (r == 3)) ? 0.0f : e3;
    }

    #pragma unroll
    for (int off = 32; off > 0; off >>= 1) s += __shfl_down(s, off, 64);
    if (lane == 0) wsum[wv] = s;
    __syncthreads();

    if (threadIdx.x == 0) ws[bt] = 0.5f * (wsum[0] + wsum[1]);
}

__global__ __launch_bounds__(256) void divloss_reduce(const float* __restrict__ ws,
                                                      float* __restrict__ out) {
    __shared__ float partial[4];
    const float4* w4 = reinterpret_cast<const float4*>(ws);  // 512 float4
    float4 v0 = w4[threadIdx.x];
    float4 v1 = w4[threadIdx.x + 256];
    float s = (v0.x + v0.y + v0.z + v0.w) + (v1.x + v1.y + v1.z + v1.w);
    #pragma unroll
    for (int off = 32; off > 0; off >>= 1) s += __shfl_down(s, off, 64);
    const int wave = threadIdx.x >> 6;
    if ((threadIdx.x & 63) == 0) partial[wave] = s;
    __syncthreads();
    if (threadIdx.x == 0) {
        float t = partial[0] + partial[1] + partial[2] + partial[3];
        out[0] = t * (1.0f / CNT);
    }
}

extern "C" void kernel_launch(void* const* d_in, const int* in_sizes, int n_in,
                              void* d_out, int out_size, void* d_ws, size_t ws_size,
                              hipStream_t stream) {
    const float* pose = (const float*)d_in[0];
    float* out = (float*)d_out;
    float* ws = (float*)d_ws;   // needs 2048 * 4 B

    divloss_pairs<<<BT_TOTAL, 128, 0, stream>>>(pose, ws);
    divloss_reduce<<<1, 256, 0, stream>>>(ws, out);
}

// Round 6
// 19.608 us; speedup vs baseline: 4.0738x; 4.0738x over previous
//
#include <hip/hip_runtime.h>

// DiversityLoss: pose (K=32, B=32, T=64, E=63) fp32.
// feat[bt,k,e] = pose[k, b, t, e], bt = b*64+t.
// loss = sum_{bt} sum_{i<j} exp(-L1(feat[bt,i], feat[bt,j])) / (BT*K*(K-1)/2)
// Off-diagonal sum computed directly (both triangles, then halve) — diagonal
// exp(0)=1 terms would absorb the ~1e-18 off-diagonal terms in fp32.
//
// Structure (round-3 validated, VGPR=68, no spills): 1 block (256 thr, 4
// waves) per bt slice; waves split the e-dim (16 elems each) keeping the 4x4
// register tile (0.5 LDS-reads/pair). Partials exchanged as float4
// (conflict-free b128), buffer aliases the feat tile.
// LESSONS ENCODED: no __launch_bounds__ min-waves (round 5: VGPR cap 64 ->
// 330 MB spill traffic, 79 us); no global atomics (round 4: agent-scope
// ACQ_REL on one line serialized retirement, 54 us).

#define KDIM 32
#define EDIM 63
#define STRIDE 68      // feat row stride (dwords): 16B-aligned; 68%32=4 spreads rows over banks
#define BT_TOTAL 2048
#define CNT 1015808.0f // 2048 * 32*31/2

__global__ __launch_bounds__(256) void divloss_pairs(const float* __restrict__ pose,
                                                     float* __restrict__ ws) {
    // 16 KB: feat tile (32*68 = 2176 dw) aliases part4 (16*64 float4 = 4096 dw).
    __shared__ float smem[4096];
    __shared__ float wsum[4];
    float* feat = smem;
    float4* part4 = reinterpret_cast<float4*>(smem);

    const int bt = blockIdx.x;
    const int wv = threadIdx.x >> 6;    // 0..3
    const int lane = threadIdx.x & 63;  // 0..63

    // Stage feat[bt]: wave wv loads rows 8*wv .. 8*wv+7 (63 floats, pad e=63 with 0).
    #pragma unroll
    for (int r = 0; r < 8; ++r) {
        const int k = 8 * wv + r;
        float v = 0.0f;
        if (lane < EDIM) v = pose[(k * BT_TOTAL + bt) * EDIM + lane];
        feat[k * STRIDE + lane] = v;
    }
    __syncthreads();

    const int ti = lane >> 3;   // rows {ti, ti+8, ti+16, ti+24}
    const int tj = lane & 7;    // cols {tj, tj+8, tj+16, tj+24}

    float acc[4][4] = {};

    // Wave wv covers e-chunks 4*wv .. 4*wv+3 (16 e-elems; wave 3 includes the pad).
    #pragma unroll
    for (int i = 0; i < 4; ++i) {
        const int ec = 4 * wv + i;
        float4 a[4], b[4];
        #pragma unroll
        for (int r = 0; r < 4; ++r)
            a[r] = *reinterpret_cast<const float4*>(&feat[(ti + 8 * r) * STRIDE + 4 * ec]);
        #pragma unroll
        for (int c = 0; c < 4; ++c)
            b[c] = *reinterpret_cast<const float4*>(&feat[(tj + 8 * c) * STRIDE + 4 * ec]);
        #pragma unroll
        for (int r = 0; r < 4; ++r)
            #pragma unroll
            for (int c = 0; c < 4; ++c) {
                acc[r][c] += fabsf(a[r].x - b[c].x) + fabsf(a[r].y - b[c].y)
                           + fabsf(a[r].z - b[c].z) + fabsf(a[r].w - b[c].w);
            }
    }

    __syncthreads();   // all feat reads done; safe to overwrite with partials

    // Exchange: wave wv writes acc[r][0..3] as one float4 at entry (wv*4+r).
    // Lane stride 16B -> conflict-free ds_write_b128.
    #pragma unroll
    for (int r = 0; r < 4; ++r)
        part4[(wv * 4 + r) * 64 + lane] = make_float4(acc[r][0], acc[r][1], acc[r][2], acc[r][3]);
    __syncthreads();

    // Wave wv finalizes acc-row r=wv (cols 0..3 in the float4 components):
    // d[c] = sum over the 4 source waves' partials; exp; mask diagonal pairs
    // (ti==tj && c==wv); accumulate both triangles.
    float d0 = 0.f, d1 = 0.f, d2 = 0.f, d3 = 0.f;
    #pragma unroll
    for (int sw = 0; sw < 4; ++sw) {
        float4 v = part4[(sw * 4 + wv) * 64 + lane];
        d0 += v.x; d1 += v.y; d2 += v.z; d3 += v.w;
    }
    float s = 0.0f;
    {
        float e0 = __expf(-d0), e1 = __expf(-d1), e2 = __expf(-d2), e3 = __expf(-d3);
        s += ((ti == tj) && (wv == 0)) ? 0.0f : e0;
        s += ((ti == tj) && (wv == 1)) ? 0.0f : e1;
        s += ((ti == tj) && (wv == 2)) ? 0.0f : e2;
        s += ((ti == tj) && (wv == 3)) ? 0.0f : e3;
    }

    #pragma unroll
    for (int off = 32; off > 0; off >>= 1) s += __shfl_down(s, off, 64);
    if (lane == 0) wsum[wv] = s;
    __syncthreads();

    if (threadIdx.x == 0)
        ws[bt] = 0.5f * (wsum[0] + wsum[1] + wsum[2] + wsum[3]);
}

__global__ __launch_bounds__(256) void divloss_reduce(const float* __restrict__ ws,
                                                      float* __restrict__ out) {
    __shared__ float partial[4];
    const float4* w4 = reinterpret_cast<const float4*>(ws);  // 512 float4
    float4 v0 = w4[threadIdx.x];
    float4 v1 = w4[threadIdx.x + 256];
    float s = (v0.x + v0.y + v0.z + v0.w) + (v1.x + v1.y + v1.z + v1.w);
    #pragma unroll
    for (int off = 32; off > 0; off >>= 1) s += __shfl_down(s, off, 64);
    const int wave = threadIdx.x >> 6;
    if ((threadIdx.x & 63) == 0) partial[wave] = s;
    __syncthreads();
    if (threadIdx.x == 0) {
        float t = partial[0] + partial[1] + partial[2] + partial[3];
        out[0] = t * (1.0f / CNT);
    }
}

extern "C" void kernel_launch(void* const* d_in, const int* in_sizes, int n_in,
                              void* d_out, int out_size, void* d_ws, size_t ws_size,
                              hipStream_t stream) {
    const float* pose = (const float*)d_in[0];
    float* out = (float*)d_out;
    float* ws = (float*)d_ws;   // needs 2048 * 4 B

    divloss_pairs<<<BT_TOTAL, 256, 0, stream>>>(pose, ws);
    divloss_reduce<<<1, 256, 0, stream>>>(ws, out);
}

// Round 7
// 19.303 us; speedup vs baseline: 4.1383x; 1.0158x over previous
//
#include <hip/hip_runtime.h>

// DiversityLoss: pose (K=32, B=32, T=64, E=63) fp32.
// feat[bt,k,e] = pose[k, b, t, e], bt = b*64+t.
// loss = sum_{bt} sum_{i<j} exp(-L1(feat[bt,i], feat[bt,j])) / (BT*K*(K-1)/2)
// Off-diagonal sum computed directly (both triangles, then halve) — diagonal
// exp(0)=1 terms would absorb the ~1e-18 off-diagonal terms in fp32.
//
// Structure: 1024 blocks (256 thr, 4 waves), each handles TWO bt slices
// (bt, bt+1024). 4 blocks/CU -> uniformly resident (round 3/6 needed 8 but
// VGPR=68 capped residency at 7 -> straggler tail). Both slices' staging
// loads issue at block start so slice-B HBM latency hides under slice-A
// compute. Waves split the e-dim (16 elems each), 4x4 register tile.
// Partials exchanged as float4 (conflict-free b128).
// LESSONS ENCODED: no __launch_bounds__ min-waves (round 5: VGPR cap ->
// 330 MB spill traffic, 79 us); no global atomics (round 4: agent-scope
// ACQ_REL serialized retirement, 54 us).

#define KDIM 32
#define EDIM 63
#define STRIDE 68      // feat row stride (dwords): 16B-aligned; 68%32=4 spreads rows over banks
#define BT_TOTAL 2048
#define NBLK 1024
#define CNT 1015808.0f // 2048 * 32*31/2

__global__ __launch_bounds__(256) void divloss_pairs(const float* __restrict__ pose,
                                                     float* __restrict__ ws) {
    __shared__ float featA[KDIM * STRIDE];   // 2176 dw
    __shared__ float featB[KDIM * STRIDE];   // 2176 dw
    __shared__ float4 part4[16 * 64];        // 4096 dw
    __shared__ float wsum[4];

    const int bt0 = blockIdx.x;
    const int bt1 = blockIdx.x + NBLK;
    const int wv = threadIdx.x >> 6;    // 0..3
    const int lane = threadIdx.x & 63;  // 0..63

    // Issue BOTH slices' staging loads up front (16 loads/lane in flight),
    // then write to LDS. Wave wv owns rows 8*wv..8*wv+7; pad e=63 with 0.
    float rA[8], rB[8];
    #pragma unroll
    for (int r = 0; r < 8; ++r) {
        const int k = 8 * wv + r;
        rA[r] = 0.0f; rB[r] = 0.0f;
        if (lane < EDIM) {
            rA[r] = pose[(k * BT_TOTAL + bt0) * EDIM + lane];
            rB[r] = pose[(k * BT_TOTAL + bt1) * EDIM + lane];
        }
    }
    #pragma unroll
    for (int r = 0; r < 8; ++r) {
        const int k = 8 * wv + r;
        featA[k * STRIDE + lane] = rA[r];
        featB[k * STRIDE + lane] = rB[r];
    }
    __syncthreads();

    const int ti = lane >> 3;   // rows {ti, ti+8, ti+16, ti+24}
    const int tj = lane & 7;    // cols {tj, tj+8, tj+16, tj+24}

    for (int sl = 0; sl < 2; ++sl) {
        const float* feat = sl ? featB : featA;

        float acc[4][4] = {};

        // Wave wv covers e-chunks 4*wv .. 4*wv+3 (16 e-elems; wave 3 has the pad).
        #pragma unroll
        for (int i = 0; i < 4; ++i) {
            const int ec = 4 * wv + i;
            float4 a[4], b[4];
            #pragma unroll
            for (int r = 0; r < 4; ++r)
                a[r] = *reinterpret_cast<const float4*>(&feat[(ti + 8 * r) * STRIDE + 4 * ec]);
            #pragma unroll
            for (int c = 0; c < 4; ++c)
                b[c] = *reinterpret_cast<const float4*>(&feat[(tj + 8 * c) * STRIDE + 4 * ec]);
            #pragma unroll
            for (int r = 0; r < 4; ++r)
                #pragma unroll
                for (int c = 0; c < 4; ++c) {
                    acc[r][c] += fabsf(a[r].x - b[c].x) + fabsf(a[r].y - b[c].y)
                               + fabsf(a[r].z - b[c].z) + fabsf(a[r].w - b[c].w);
                }
        }

        __syncthreads();   // prior part4 readers (sl=0 finalize) done before overwrite

        // Exchange: wave wv writes acc[r][0..3] as one float4 at entry (wv*4+r).
        // Lane stride 16B -> conflict-free ds_write_b128.
        #pragma unroll
        for (int r = 0; r < 4; ++r)
            part4[(wv * 4 + r) * 64 + lane] =
                make_float4(acc[r][0], acc[r][1], acc[r][2], acc[r][3]);
        __syncthreads();

        // Wave wv finalizes acc-row r=wv: d[c] = sum of the 4 waves' partials;
        // exp; mask diagonal pairs (ti==tj && c==wv); accumulate both triangles.
        float d0 = 0.f, d1 = 0.f, d2 = 0.f, d3 = 0.f;
        #pragma unroll
        for (int sw = 0; sw < 4; ++sw) {
            float4 v = part4[(sw * 4 + wv) * 64 + lane];
            d0 += v.x; d1 += v.y; d2 += v.z; d3 += v.w;
        }
        float s = 0.0f;
        {
            float e0 = __expf(-d0), e1 = __expf(-d1), e2 = __expf(-d2), e3 = __expf(-d3);
            s += ((ti == tj) && (wv == 0)) ? 0.0f : e0;
            s += ((ti == tj) && (wv == 1)) ? 0.0f : e1;
            s += ((ti == tj) && (wv == 2)) ? 0.0f : e2;
            s += ((ti == tj) && (wv == 3)) ? 0.0f : e3;
        }

        #pragma unroll
        for (int off = 32; off > 0; off >>= 1) s += __shfl_down(s, off, 64);
        if (lane == 0) wsum[wv] = s;
        __syncthreads();

        if (threadIdx.x == 0)
            ws[sl ? bt1 : bt0] = 0.5f * (wsum[0] + wsum[1] + wsum[2] + wsum[3]);
    }
}

__global__ __launch_bounds__(256) void divloss_reduce(const float* __restrict__ ws,
                                                      float* __restrict__ out) {
    __shared__ float partial[4];
    const float4* w4 = reinterpret_cast<const float4*>(ws);  // 512 float4
    float4 v0 = w4[threadIdx.x];
    float4 v1 = w4[threadIdx.x + 256];
    float s = (v0.x + v0.y + v0.z + v0.w) + (v1.x + v1.y + v1.z + v1.w);
    #pragma unroll
    for (int off = 32; off > 0; off >>= 1) s += __shfl_down(s, off, 64);
    const int wave = threadIdx.x >> 6;
    if ((threadIdx.x & 63) == 0) partial[wave] = s;
    __syncthreads();
    if (threadIdx.x == 0) {
        float t = partial[0] + partial[1] + partial[2] + partial[3];
        out[0] = t * (1.0f / CNT);
    }
}

extern "C" void kernel_launch(void* const* d_in, const int* in_sizes, int n_in,
                              void* d_out, int out_size, void* d_ws, size_t ws_size,
                              hipStream_t stream) {
    const float* pose = (const float*)d_in[0];
    float* out = (float*)d_out;
    float* ws = (float*)d_ws;   // needs 2048 * 4 B

    divloss_pairs<<<NBLK, 256, 0, stream>>>(pose, ws);
    divloss_reduce<<<1, 256, 0, stream>>>(ws, out);
}

// Round 8
// 18.671 us; speedup vs baseline: 4.2783x; 1.0338x over previous
//
#include <hip/hip_runtime.h>

// DiversityLoss: pose (K=32, B=32, T=64, E=63) fp32.
// feat[bt,k,e] = pose[k, b, t, e], bt = b*64+t.
// loss = sum_{bt} sum_{i<j} exp(-L1(feat[bt,i], feat[bt,j])) / (BT*K*(K-1)/2)
// Off-diagonal sum computed directly (both triangles, then halve) — diagonal
// exp(0)=1 terms would absorb the ~1e-18 off-diagonal terms in fp32.
//
// Structure: 1024 blocks (256 thr, 4 waves), each handles TWO bt slices.
// Each wave's lanes 0..31 work on slice A, lanes 32..63 on slice B; per lane
// an 8x4 pair tile (i = rg+4*rr, j = cg+8*cc). A 16B e-chunk costs 12
// ds_read_b128 per wave COVERING BOTH SLICES -> 96 wave-reads/slice vs 128
// for the 4x4 tile (25% less LDS-pipe, the dominant term at ~5.1 us chip).
// Row/col labels chosen so each read instruction hits stride-4 distinct
// banks with only 2-way slice aliasing (free). Partials exchanged as float4
// (lane-stride-16B, conflict-free) in a 32 KB buffer unioned over the feat
// tiles (reused only after all feat reads).
// LESSONS ENCODED: no __launch_bounds__ min-waves (round 5: VGPR cap ->
// 330 MB spill traffic, 79 us); no global atomics (round 4: agent-scope
// ACQ_REL serialized retirement, 54 us); VGPR must stay <=128 (4 waves/SIMD
// boundary) for 4 blocks/CU residency.

#define KDIM 32
#define EDIM 63
#define STRIDE 68      // feat row stride (dwords): 16B-aligned; 68%32=4 spreads rows over banks
#define BT_TOTAL 2048
#define NBLK 1024
#define CNT 1015808.0f // 2048 * 32*31/2

__global__ __launch_bounds__(256) void divloss_pairs(const float* __restrict__ pose,
                                                     float* __restrict__ ws) {
    // Union: feat (2 slices x 32 x 68 dw = 4352 dw) / part4 (2048 float4 = 32 KB).
    __shared__ float4 smem4[2048];
    __shared__ float wsumA[4], wsumB[4];
    float* smem = reinterpret_cast<float*>(smem4);

    const int bt0 = blockIdx.x;
    const int bt1 = blockIdx.x + NBLK;
    const int wv = threadIdx.x >> 6;    // 0..3
    const int lane = threadIdx.x & 63;  // 0..63

    // Stage both slices (issue all 16 loads first, then LDS writes).
    float rA[8], rB[8];
    #pragma unroll
    for (int r = 0; r < 8; ++r) {
        const int k = 8 * wv + r;
        rA[r] = 0.0f; rB[r] = 0.0f;
        if (lane < EDIM) {
            rA[r] = pose[(k * BT_TOTAL + bt0) * EDIM + lane];
            rB[r] = pose[(k * BT_TOTAL + bt1) * EDIM + lane];
        }
    }
    #pragma unroll
    for (int r = 0; r < 8; ++r) {
        const int k = 8 * wv + r;
        smem[k * STRIDE + lane] = rA[r];                 // slice A rows
        smem[KDIM * STRIDE + k * STRIDE + lane] = rB[r]; // slice B rows
    }
    __syncthreads();

    const int sl = lane >> 5;           // 0: slice A, 1: slice B
    const int hl = lane & 31;
    const int rg = hl >> 3;             // 0..3  (i = rg + 4*rr)
    const int cg = hl & 7;              // 0..7  (j = cg + 8*cc)
    const float* feat = smem + sl * (KDIM * STRIDE);

    float acc[8][4] = {};               // acc[rr][cc] for pair (rg+4rr, cg+8cc)

    // Wave wv covers e-chunks 4*wv .. 4*wv+3 (16 e-elems; wave 3 has the pad).
    #pragma unroll
    for (int ic = 0; ic < 4; ++ic) {
        const int e0 = 4 * (4 * wv + ic);   // dword column base
        float4 b[4];
        #pragma unroll
        for (int cc = 0; cc < 4; ++cc)
            b[cc] = *reinterpret_cast<const float4*>(&feat[(cg + 8 * cc) * STRIDE + e0]);
        #pragma unroll
        for (int half = 0; half < 2; ++half) {   // a in two groups of 4 (VGPR cap)
            float4 a[4];
            #pragma unroll
            for (int ra = 0; ra < 4; ++ra)
                a[ra] = *reinterpret_cast<const float4*>(
                    &feat[(rg + 16 * half + 4 * ra) * STRIDE + e0]);
            #pragma unroll
            for (int ra = 0; ra < 4; ++ra)
                #pragma unroll
                for (int cc = 0; cc < 4; ++cc)
                    acc[4 * half + ra][cc] +=
                          fabsf(a[ra].x - b[cc].x) + fabsf(a[ra].y - b[cc].y)
                        + fabsf(a[ra].z - b[cc].z) + fabsf(a[ra].w - b[cc].w);
        }
    }

    __syncthreads();   // all feat reads done; smem reused as part4

    // Exchange: wave wv writes acc[rr][0..3] as float4 at [(wv*8+rr)*64+lane].
    #pragma unroll
    for (int rr = 0; rr < 8; ++rr)
        smem4[(wv * 8 + rr) * 64 + lane] =
            make_float4(acc[rr][0], acc[rr][1], acc[rr][2], acc[rr][3]);
    __syncthreads();

    // Wave wv finalizes rr in {2wv, 2wv+1}: d = sum of 4 wave-partials; exp;
    // mask diagonal (i == j); accumulate both triangles.
    float s = 0.0f;
    #pragma unroll
    for (int ent = 0; ent < 2; ++ent) {
        const int rre = 2 * wv + ent;
        float dx = 0.f, dy = 0.f, dz = 0.f, dw = 0.f;
        #pragma unroll
        for (int w2 = 0; w2 < 4; ++w2) {
            float4 v = smem4[(w2 * 8 + rre) * 64 + lane];
            dx += v.x; dy += v.y; dz += v.z; dw += v.w;
        }
        const int i = rg + 4 * rre;
        float e0v = __expf(-dx), e1v = __expf(-dy), e2v = __expf(-dz), e3v = __expf(-dw);
        s += (i == cg)      ? 0.0f : e0v;
        s += (i == cg + 8)  ? 0.0f : e1v;
        s += (i == cg + 16) ? 0.0f : e2v;
        s += (i == cg + 24) ? 0.0f : e3v;
    }

    // Reduce within 32-lane groups (A: lanes 0..31, B: lanes 32..63).
    #pragma unroll
    for (int off = 16; off > 0; off >>= 1) s += __shfl_down(s, off, 32);
    if (hl == 0) { if (sl == 0) wsumA[wv] = s; else wsumB[wv] = s; }
    __syncthreads();

    if (threadIdx.x == 0) {
        ws[bt0] = 0.5f * (wsumA[0] + wsumA[1] + wsumA[2] + wsumA[3]);
        ws[bt1] = 0.5f * (wsumB[0] + wsumB[1] + wsumB[2] + wsumB[3]);
    }
}

__global__ __launch_bounds__(256) void divloss_reduce(const float* __restrict__ ws,
                                                      float* __restrict__ out) {
    __shared__ float partial[4];
    const float4* w4 = reinterpret_cast<const float4*>(ws);  // 512 float4
    float4 v0 = w4[threadIdx.x];
    float4 v1 = w4[threadIdx.x + 256];
    float s = (v0.x + v0.y + v0.z + v0.w) + (v1.x + v1.y + v1.z + v1.w);
    #pragma unroll
    for (int off = 32; off > 0; off >>= 1) s += __shfl_down(s, off, 64);
    const int wave = threadIdx.x >> 6;
    if ((threadIdx.x & 63) == 0) partial[wave] = s;
    __syncthreads();
    if (threadIdx.x == 0) {
        float t = partial[0] + partial[1] + partial[2] + partial[3];
        out[0] = t * (1.0f / CNT);
    }
}

extern "C" void kernel_launch(void* const* d_in, const int* in_sizes, int n_in,
                              void* d_out, int out_size, void* d_ws, size_t ws_size,
                              hipStream_t stream) {
    const float* pose = (const float*)d_in[0];
    float* out = (float*)d_out;
    float* ws = (float*)d_ws;   // needs 2048 * 4 B

    divloss_pairs<<<NBLK, 256, 0, stream>>>(pose, ws);
    divloss_reduce<<<1, 256, 0, stream>>>(ws, out);
}